// Round 4
// baseline (819.950 us; speedup 1.0000x reference)
//
#include <hip/hip_runtime.h>
#include <math.h>

// Problem constants (fixed by setup_inputs)
constexpr int B_ = 4, S_ = 8192, D_ = 1024, H_ = 1024, O_ = 1024;

typedef __bf16 bf16x8 __attribute__((ext_vector_type(8)));
typedef float  f32x4  __attribute__((ext_vector_type(4)));

__device__ __forceinline__ float softplusf(float x) {
    if (x > 20.f) return x;
    if (x < -20.f) return expf(x);
    return log1pf(expf(x));
}

// ---------------------------------------------------------------------------
// fp32 -> bf16 conversion (8 elems/thread, 16B stores)
// ---------------------------------------------------------------------------
__global__ __launch_bounds__(256) void cvt_bf16(const float* __restrict__ src,
                                                __bf16* __restrict__ dst, int n8) {
    int i = blockIdx.x * blockDim.x + threadIdx.x;
    if (i >= n8) return;
    const float4* s = (const float4*)src + (size_t)i * 2;
    float4 a = s[0], b = s[1];
    bf16x8 v = {(__bf16)a.x, (__bf16)a.y, (__bf16)a.z, (__bf16)a.w,
                (__bf16)b.x, (__bf16)b.y, (__bf16)b.z, (__bf16)b.w};
    *((bf16x8*)dst + i) = v;
}

// ---------------------------------------------------------------------------
// Barrier-free register-resident bf16 MFMA GEMM fused with elementwise chain
// and s-reduction.
//   h_last[b,h] = F * (0.5 + sum_s term_s)
//   term = (1+e^{-f})/(1+e^{-i}) * g(h);  g(h)= h>=0 ? h+0.5 : e^h/(1+e^h)
//   F (at s=S-1) = (1+e^{-i}) / ((1+e^{-f}) + (1+e^{-i}))
//
// Block: 256 thr = 4 waves (2m x 2n). Wave tile: 64(s) x 32(h) x 3 gates.
// A and B fragments loaded straight from global (row-major matches the
// mfma_f32_16x16x32_bf16 operand layout: lane(lr,quad) holds
// [row=lr][k=quad*8..+8] = one dwordx4). No LDS, no __syncthreads in the
// K-loop -> compiler emits fine-grained vmcnt, true load/MFMA overlap.
// K fully unrolled: all load offsets are compile-time (span 2 KB < 4 KB imm).
// ---------------------------------------------------------------------------
constexpr int BM = 128, BN = 64, BK = 32, NK = D_ / BK;   // NK = 32

__global__ __launch_bounds__(256, 2) void gemm_fused_bf16(
    const __bf16* __restrict__ xb, const __bf16* __restrict__ wb,
    float* __restrict__ acc_ws, float* __restrict__ F_ws)
{
    __shared__ float colsum[BN];

    // XCD-aware swizzle: blocks sharing an h-panel cluster on one XCD so the
    // 384 KB B-panel stays hot in that XCD's L2 (2 panels/XCD = 768 KB).
    int id  = blockIdx.x;
    int xcd = id & 7;
    int j   = id >> 3;
    int hb  = (xcd << 1) | (j & 1);  j >>= 1;
    int sb  = j & 63;
    int b   = j >> 6;

    const int h0   = hb * BN;
    const int s0   = sb * BM;
    const int tid  = threadIdx.x;
    const int lane = tid & 63;
    const int wid  = tid >> 6;
    const int wm   = wid >> 1;   // 0..1 : s offset wm*64
    const int wn   = wid & 1;    // 0..1 : h offset wn*32
    const int lr   = lane & 15;
    const int quad = lane >> 4;

    if (tid < BN) colsum[tid] = 0.f;

    // Base fragment pointers (fixed; K-loop uses constant indices).
    // Chunk k lives at element offset k*BK = k*4 bf16x8-units.
    const bf16x8* pa[4];
    #pragma unroll
    for (int t = 0; t < 4; ++t)
        pa[t] = (const bf16x8*)(xb +
            ((size_t)(b * S_ + s0 + wm * 64 + t * 16 + lr)) * D_ + quad * 8);
    const bf16x8* pb[6];
    #pragma unroll
    for (int g = 0; g < 3; ++g)
        #pragma unroll
        for (int n = 0; n < 2; ++n)
            pb[g * 2 + n] = (const bf16x8*)(wb +
                ((size_t)g * H_ + h0 + wn * 32 + n * 16 + lr) * D_ + quad * 8);

    f32x4 acc[3][4][2] = {};

    // 2-deep register double buffer, software-pipelined by the scheduler.
    bf16x8 Af[2][4], Bf[2][6];
    #pragma unroll
    for (int t = 0; t < 4; ++t) { Af[0][t] = pa[t][0]; Af[1][t] = pa[t][4]; }
    #pragma unroll
    for (int u = 0; u < 6; ++u) { Bf[0][u] = pb[u][0]; Bf[1][u] = pb[u][4]; }

    #pragma unroll
    for (int k = 0; k < NK; ++k) {
        const int p = k & 1;
        bf16x8 a0 = Af[p][0], a1 = Af[p][1], a2 = Af[p][2], a3 = Af[p][3];
        bf16x8 b0 = Bf[p][0], b1 = Bf[p][1], b2 = Bf[p][2],
               b3 = Bf[p][3], b4 = Bf[p][4], b5 = Bf[p][5];
        if (k + 2 < NK) {
            #pragma unroll
            for (int t = 0; t < 4; ++t) Af[p][t] = pa[t][(k + 2) * 4];
            #pragma unroll
            for (int u = 0; u < 6; ++u) Bf[p][u] = pb[u][(k + 2) * 4];
        }
        // gate f (b0,b1), i (b2,b3), h (b4,b5); n = even/odd
        acc[0][0][0] = __builtin_amdgcn_mfma_f32_16x16x32_bf16(a0, b0, acc[0][0][0], 0, 0, 0);
        acc[0][1][0] = __builtin_amdgcn_mfma_f32_16x16x32_bf16(a1, b0, acc[0][1][0], 0, 0, 0);
        acc[0][2][0] = __builtin_amdgcn_mfma_f32_16x16x32_bf16(a2, b0, acc[0][2][0], 0, 0, 0);
        acc[0][3][0] = __builtin_amdgcn_mfma_f32_16x16x32_bf16(a3, b0, acc[0][3][0], 0, 0, 0);
        acc[0][0][1] = __builtin_amdgcn_mfma_f32_16x16x32_bf16(a0, b1, acc[0][0][1], 0, 0, 0);
        acc[0][1][1] = __builtin_amdgcn_mfma_f32_16x16x32_bf16(a1, b1, acc[0][1][1], 0, 0, 0);
        acc[0][2][1] = __builtin_amdgcn_mfma_f32_16x16x32_bf16(a2, b1, acc[0][2][1], 0, 0, 0);
        acc[0][3][1] = __builtin_amdgcn_mfma_f32_16x16x32_bf16(a3, b1, acc[0][3][1], 0, 0, 0);
        acc[1][0][0] = __builtin_amdgcn_mfma_f32_16x16x32_bf16(a0, b2, acc[1][0][0], 0, 0, 0);
        acc[1][1][0] = __builtin_amdgcn_mfma_f32_16x16x32_bf16(a1, b2, acc[1][1][0], 0, 0, 0);
        acc[1][2][0] = __builtin_amdgcn_mfma_f32_16x16x32_bf16(a2, b2, acc[1][2][0], 0, 0, 0);
        acc[1][3][0] = __builtin_amdgcn_mfma_f32_16x16x32_bf16(a3, b2, acc[1][3][0], 0, 0, 0);
        acc[1][0][1] = __builtin_amdgcn_mfma_f32_16x16x32_bf16(a0, b3, acc[1][0][1], 0, 0, 0);
        acc[1][1][1] = __builtin_amdgcn_mfma_f32_16x16x32_bf16(a1, b3, acc[1][1][1], 0, 0, 0);
        acc[1][2][1] = __builtin_amdgcn_mfma_f32_16x16x32_bf16(a2, b3, acc[1][2][1], 0, 0, 0);
        acc[1][3][1] = __builtin_amdgcn_mfma_f32_16x16x32_bf16(a3, b3, acc[1][3][1], 0, 0, 0);
        acc[2][0][0] = __builtin_amdgcn_mfma_f32_16x16x32_bf16(a0, b4, acc[2][0][0], 0, 0, 0);
        acc[2][1][0] = __builtin_amdgcn_mfma_f32_16x16x32_bf16(a1, b4, acc[2][1][0], 0, 0, 0);
        acc[2][2][0] = __builtin_amdgcn_mfma_f32_16x16x32_bf16(a2, b4, acc[2][2][0], 0, 0, 0);
        acc[2][3][0] = __builtin_amdgcn_mfma_f32_16x16x32_bf16(a3, b4, acc[2][3][0], 0, 0, 0);
        acc[2][0][1] = __builtin_amdgcn_mfma_f32_16x16x32_bf16(a0, b5, acc[2][0][1], 0, 0, 0);
        acc[2][1][1] = __builtin_amdgcn_mfma_f32_16x16x32_bf16(a1, b5, acc[2][1][1], 0, 0, 0);
        acc[2][2][1] = __builtin_amdgcn_mfma_f32_16x16x32_bf16(a2, b5, acc[2][2][1], 0, 0, 0);
        acc[2][3][1] = __builtin_amdgcn_mfma_f32_16x16x32_bf16(a3, b5, acc[2][3][1], 0, 0, 0);
    }

    // --- epilogue: exp-form elementwise chain + column (s) reduction ------
    // C/D layout: col = lane&15, row = quad*4 + reg  [m89-verified]
    const bool lastS = (s0 + BM == S_);
    float vsum[2] = {0.f, 0.f};
    #pragma unroll
    for (int n = 0; n < 2; ++n) {
        #pragma unroll
        for (int t = 0; t < 4; ++t) {
            f32x4 fv = acc[0][t][n], iv = acc[1][t][n], hv = acc[2][t][n];
            #pragma unroll
            for (int r = 0; r < 4; ++r) {
                float ef = __expf(-fv[r]);
                float ei = __expf(-iv[r]);
                float af1 = 1.f + ef, ai1 = 1.f + ei;
                float h  = hv[r];
                float eh = __expf(h);
                float g  = (h >= 0.f) ? (h + 0.5f)
                                      : (eh * __builtin_amdgcn_rcpf(1.f + eh));
                vsum[n] += af1 * __builtin_amdgcn_rcpf(ai1) * g;
                if (lastS && wm == 1 && t == 3 && quad == 3 && r == 3) {
                    // this element is global row s = S-1
                    F_ws[(size_t)b * H_ + h0 + wn * 32 + n * 16 + lr] =
                        ai1 * __builtin_amdgcn_rcpf(af1 + ai1);
                }
            }
        }
    }
    __syncthreads();   // colsum init visible to all waves
    #pragma unroll
    for (int n = 0; n < 2; ++n) {
        float v = vsum[n];
        v += __shfl_xor(v, 16, 64);
        v += __shfl_xor(v, 32, 64);
        if (quad == 0) atomicAdd(&colsum[wn * 32 + n * 16 + lr], v);
    }
    __syncthreads();
    if (tid < BN)
        atomicAdd(&acc_ws[(size_t)b * H_ + h0 + tid], colsum[tid]);
}

// out[b,o] = b_out[o] + sum_h w_out[o,h] * F[b,h]*(0.5 + acc[b,h])
__global__ __launch_bounds__(256) void out_gemv(
    const float* __restrict__ wout, const float* __restrict__ bout,
    const float* __restrict__ acc_ws, const float* __restrict__ F_ws,
    float* __restrict__ out)
{
    const int lane = threadIdx.x & 63;
    const int o = blockIdx.x * 4 + (threadIdx.x >> 6);
    float s[B_] = {};
    for (int h = lane; h < H_; h += 64) {
        float w = wout[(size_t)o * H_ + h];
        #pragma unroll
        for (int b = 0; b < B_; ++b) {
            float hv = F_ws[b * H_ + h] * (0.5f + acc_ws[b * H_ + h]);
            s[b] = fmaf(w, hv, s[b]);
        }
    }
    #pragma unroll
    for (int b = 0; b < B_; ++b)
        #pragma unroll
        for (int off = 32; off > 0; off >>= 1)
            s[b] += __shfl_down(s[b], off, 64);
    if (lane == 0) {
        float bo = bout[o];
        #pragma unroll
        for (int b = 0; b < B_; ++b)
            out[(size_t)b * O_ + o] = s[b] + bo;
    }
}

// ---------------------------------------------------------------------------
// fp32 fallback (round-1 kernel) -- used only if ws_size is too small
// ---------------------------------------------------------------------------
constexpr int TS = 64, TH = 64, TK = 16, LDP = 68;

__global__ __launch_bounds__(256) void fused_gemm_reduce(
    const float* __restrict__ x, const float* __restrict__ win,
    float* __restrict__ acc_ws, float* __restrict__ F_ws)
{
    __shared__ __align__(16) float As[TK][LDP];
    __shared__ __align__(16) float Wf[TK][LDP];
    __shared__ __align__(16) float Wi[TK][LDP];
    __shared__ __align__(16) float Wh[TK][LDP];
    __shared__ float colsum[TH];

    const int b  = blockIdx.z;
    const int s0 = blockIdx.x * TS;
    const int h0 = blockIdx.y * TH;
    const int tid = threadIdx.x;
    const int tx = tid & 15;
    const int ty = tid >> 4;

    float accf[4][4] = {};
    float acci[4][4] = {};
    float acch[4][4] = {};

    const int lrow = tid >> 2;
    const int lk4  = (tid & 3) << 2;

    const float* xp  = x   + ((size_t)b * S_ + (s0 + lrow)) * D_ + lk4;
    const float* wfp = win + (size_t)(h0 + lrow) * D_ + lk4;
    const float* wip = wfp + (size_t)H_ * D_;
    const float* whp = wip + (size_t)H_ * D_;

    for (int k0 = 0; k0 < D_; k0 += TK) {
        float4 va = *(const float4*)(xp  + k0);
        float4 vf = *(const float4*)(wfp + k0);
        float4 vi = *(const float4*)(wip + k0);
        float4 vh = *(const float4*)(whp + k0);
        __syncthreads();
        As[lk4+0][lrow]=va.x; As[lk4+1][lrow]=va.y; As[lk4+2][lrow]=va.z; As[lk4+3][lrow]=va.w;
        Wf[lk4+0][lrow]=vf.x; Wf[lk4+1][lrow]=vf.y; Wf[lk4+2][lrow]=vf.z; Wf[lk4+3][lrow]=vf.w;
        Wi[lk4+0][lrow]=vi.x; Wi[lk4+1][lrow]=vi.y; Wi[lk4+2][lrow]=vi.z; Wi[lk4+3][lrow]=vi.w;
        Wh[lk4+0][lrow]=vh.x; Wh[lk4+1][lrow]=vh.y; Wh[lk4+2][lrow]=vh.z; Wh[lk4+3][lrow]=vh.w;
        __syncthreads();
        #pragma unroll
        for (int k = 0; k < TK; ++k) {
            float4 a4 = *(const float4*)&As[k][ty << 2];
            float4 f4 = *(const float4*)&Wf[k][tx << 2];
            float4 i4 = *(const float4*)&Wi[k][tx << 2];
            float4 h4 = *(const float4*)&Wh[k][tx << 2];
            float a[4]  = {a4.x, a4.y, a4.z, a4.w};
            float wf[4] = {f4.x, f4.y, f4.z, f4.w};
            float wi[4] = {i4.x, i4.y, i4.z, i4.w};
            float wh[4] = {h4.x, h4.y, h4.z, h4.w};
            #pragma unroll
            for (int r = 0; r < 4; ++r)
                #pragma unroll
                for (int c = 0; c < 4; ++c) {
                    accf[r][c] = fmaf(a[r], wf[c], accf[r][c]);
                    acci[r][c] = fmaf(a[r], wi[c], acci[r][c]);
                    acch[r][c] = fmaf(a[r], wh[c], acch[r][c]);
                }
        }
    }

    const bool last_s = (s0 + TS == S_);
    float cval[4] = {0.f, 0.f, 0.f, 0.f};
    #pragma unroll
    for (int c = 0; c < 4; ++c)
        #pragma unroll
        for (int r = 0; r < 4; ++r) {
            float f = accf[r][c], i = acci[r][c], h = acch[r][c];
            float d  = softplusf(-f) - softplusf(-i);
            float lg = (h >= 0.f) ? logf(h + 0.5f) : -softplusf(-h);
            cval[c] += expf(d + lg);
            if (last_s && ty == 15 && r == 3)
                F_ws[(size_t)b * H_ + h0 + (tx << 2) + c] = expf(-softplusf(d));
        }
    if (tid < TH) colsum[tid] = 0.f;
    __syncthreads();
    #pragma unroll
    for (int c = 0; c < 4; ++c)
        atomicAdd(&colsum[(tx << 2) + c], cval[c]);
    __syncthreads();
    if (tid < TH)
        atomicAdd(&acc_ws[(size_t)b * H_ + h0 + tid], colsum[tid]);
}

extern "C" void kernel_launch(void* const* d_in, const int* in_sizes, int n_in,
                              void* d_out, int out_size, void* d_ws, size_t ws_size,
                              hipStream_t stream) {
    const float* x    = (const float*)d_in[0];
    const float* w_in = (const float*)d_in[1];
    const float* wout = (const float*)d_in[2];
    const float* bout = (const float*)d_in[3];
    float* out = (float*)d_out;

    float* acc_ws = (float*)d_ws;                 // [B,H] running sums
    float* F_ws   = acc_ws + (size_t)B_ * H_;     // [B,H] exp(log_f at s=S-1)

    hipMemsetAsync(d_ws, 0, 2 * (size_t)B_ * H_ * sizeof(float), stream);

    const size_t nx = (size_t)B_ * S_ * D_;       // 33.5M
    const size_t nw = (size_t)3 * H_ * D_;        // 3.1M
    const size_t bf_off = 32768;                  // past acc/F, 16B aligned
    const size_t need = bf_off + (nx + nw) * sizeof(__bf16);

    if (ws_size >= need) {
        __bf16* xb = (__bf16*)((char*)d_ws + bf_off);
        __bf16* wb = xb + nx;
        cvt_bf16<<<(int)(nx / 8 / 256), 256, 0, stream>>>(x, xb, (int)(nx / 8));
        cvt_bf16<<<(int)(nw / 8 / 256), 256, 0, stream>>>(w_in, wb, (int)(nw / 8));
        gemm_fused_bf16<<<(H_ / BN) * (S_ / BM) * B_, 256, 0, stream>>>(
            xb, wb, acc_ws, F_ws);
    } else {
        dim3 grid(S_ / TS, H_ / TH, B_);
        fused_gemm_reduce<<<grid, 256, 0, stream>>>(x, w_in, acc_ws, F_ws);
    }
    out_gemv<<<O_ / 4, 256, 0, stream>>>(wout, bout, acc_ws, F_ws, out);
}

// Round 5
// 465.714 us; speedup vs baseline: 1.7606x; 1.7606x over previous
//
#include <hip/hip_runtime.h>
#include <math.h>

// Problem constants (fixed by setup_inputs)
constexpr int B_ = 4, S_ = 8192, D_ = 1024, H_ = 1024, O_ = 1024;

typedef __bf16 bf16x8 __attribute__((ext_vector_type(8)));
typedef float  f32x4  __attribute__((ext_vector_type(4)));

__device__ __forceinline__ float softplusf(float x) {
    if (x > 20.f) return x;
    if (x < -20.f) return expf(x);
    return log1pf(expf(x));
}

// ---------------------------------------------------------------------------
// fp32 -> bf16 conversion for BOTH x and w_in in one launch
// (8 elems/thread, 16B stores)
// ---------------------------------------------------------------------------
__global__ __launch_bounds__(256) void cvt_bf16_2(
    const float* __restrict__ srcA, __bf16* __restrict__ dstA, int nA8,
    const float* __restrict__ srcB, __bf16* __restrict__ dstB, int nB8) {
    int i = blockIdx.x * blockDim.x + threadIdx.x;
    const float* src; __bf16* dst;
    if (i < nA8) { src = srcA; dst = dstA; }
    else { i -= nA8; if (i >= nB8) return; src = srcB; dst = dstB; }
    const float4* s = (const float4*)src + (size_t)i * 2;
    float4 a = s[0], b = s[1];
    bf16x8 v = {(__bf16)a.x, (__bf16)a.y, (__bf16)a.z, (__bf16)a.w,
                (__bf16)b.x, (__bf16)b.y, (__bf16)b.z, (__bf16)b.w};
    *((bf16x8*)dst + i) = v;
}

// ---------------------------------------------------------------------------
// bf16 MFMA GEMM (z = x @ w_in^T for 3 gates) fused with elementwise chain
// and s-reduction, double-buffered LDS, exp-form epilogue.
//   h_last[b,h] = F * (0.5 + sum_s term_s)
//   term = (1+e^{-f})/(1+e^{-i}) * g(h);  g(h)= h>=0 ? h+0.5 : e^h/(1+e^h)
//   F (at s=S-1) = (1+e^{-i}) / ((1+e^{-f}) + (1+e^{-i}))
// Block tile: BM=128 (s) x BN=64 (h), BK=32. 4 waves, each 64s x 32h.
//
// Block-id mapping (XCD locality): all 16 h-tiles of one A panel get ids
// congruent mod 8 -> same XCD under round-robin dispatch, so the 256 KB
// A panel is fetched into ONE XCD's L2 and reused by its 16 h-blocks.
// ---------------------------------------------------------------------------
constexpr int BM = 128, BN = 64, BK = 32;
constexpr int BUF_ELEMS = (BM + 3 * BN) * BK;  // 10240 bf16 = 20 KB

__global__ __launch_bounds__(256) void gemm_fused_bf16(
    const __bf16* __restrict__ xb, const __bf16* __restrict__ wb,
    float* __restrict__ acc_ws, float* __restrict__ F_ws)
{
    __shared__ __bf16 sbuf[2][BUF_ELEMS];   // 40 KB double buffer
    __shared__ float colsum[BN];

    // decode: id = ((pl*16 + hb) * 8) + c ; panel = c*32 + pl
    const int id = blockIdx.x;
    const int c  = id & 7;
    const int q  = id >> 3;          // 0..511
    const int hb = q & 15;
    const int pl = q >> 4;           // 0..31
    const int panel = c * 32 + pl;   // 0..255
    const int sb = panel & 63;
    const int b  = panel >> 6;

    const int h0   = hb * BN;
    const int s0   = sb * BM;
    const int tid  = threadIdx.x;
    const int lane = tid & 63;
    const int wid  = tid >> 6;
    const int wm   = wid >> 1;  // 0..1 : s offset wm*64
    const int wn   = wid & 1;   // 0..1 : h offset wn*32
    const int lr   = lane & 15;
    const int quad = lane >> 4;

    if (tid < BN) colsum[tid] = 0.f;

    // --- staging setup: wave handles wave-loads u = wid*5 + j -------------
    // Each wave-load: 64 lanes x 16B -> 1KB = 16 rows of 32 bf16.
    // LDS dest is wave-uniform base + lane*16 (HW). Global quad
    // q = sp ^ ((row>>1)&3) goes into slot sp -> compute-side reads are
    // 2-way-max bank aliased (free).
    const __bf16* gptr[5];
    __bf16* lptr0[5];
    __bf16* lptr1[5];
    #pragma unroll
    for (int j = 0; j < 5; ++j) {
        int u  = wid * 5 + j;        // 0..19 : 0-7 = A chunks, 8-19 = B chunks
        int rl = lane >> 2;          // row within 16-row chunk
        int sp = lane & 3;           // slot position
        int off;
        if (u < 8) {
            int row = u * 16 + rl;   // 0..127
            int qq  = sp ^ ((row >> 1) & 3);
            gptr[j] = xb + ((size_t)(b * S_ + s0 + row)) * D_ + qq * 8;
            off = u * 512;
        } else {
            int v   = u - 8;         // g = v>>2, chunk cc = v&3
            int row = (v & 3) * 16 + rl;  // 0..63
            int qq  = sp ^ ((row >> 1) & 3);
            gptr[j] = wb + (size_t)(v >> 2) * H_ * D_ + (size_t)(h0 + row) * D_ + qq * 8;
            off = BM * BK + v * 512;
        }
        lptr0[j] = &sbuf[0][off];
        lptr1[j] = &sbuf[1][off];
    }

    // --- loop-invariant fragment element-offsets ---------------------------
    int aofs[4];
    #pragma unroll
    for (int t = 0; t < 4; ++t) {
        int row  = wm * 64 + t * 16 + lr;
        int slot = quad ^ ((row >> 1) & 3);
        aofs[t] = row * BK + slot * 8;
    }
    int bofs[3][2];
    #pragma unroll
    for (int g = 0; g < 3; ++g)
        #pragma unroll
        for (int n = 0; n < 2; ++n) {
            int row  = wn * 32 + n * 16 + lr;
            int slot = quad ^ ((row >> 1) & 3);
            bofs[g][n] = BM * BK + g * (BN * BK) + row * BK + slot * 8;
        }

    f32x4 acc[3][4][2] = {};

    auto issue_loads = [&](int nxt) {
        #pragma unroll
        for (int j = 0; j < 5; ++j) {
            __builtin_amdgcn_global_load_lds(
                (const __attribute__((address_space(1))) void*)gptr[j],
                (__attribute__((address_space(3))) void*)(nxt ? lptr1[j] : lptr0[j]),
                16, 0, 0);
            gptr[j] += BK;
        }
    };
    auto compute = [&](const __bf16* base) {
        bf16x8 af[4];
        #pragma unroll
        for (int t = 0; t < 4; ++t) af[t] = *(const bf16x8*)(base + aofs[t]);
        #pragma unroll
        for (int g = 0; g < 3; ++g)
            #pragma unroll
            for (int n = 0; n < 2; ++n) {
                bf16x8 bfrag = *(const bf16x8*)(base + bofs[g][n]);
                #pragma unroll
                for (int t = 0; t < 4; ++t)
                    acc[g][t][n] = __builtin_amdgcn_mfma_f32_16x16x32_bf16(
                        af[t], bfrag, acc[g][t][n], 0, 0, 0);
            }
    };

    issue_loads(0);  // k-chunk 0 -> buf0
    for (int k0 = 0; k0 < D_ / BK; k0 += 2) {
        // barrier AFTER compute(prev) and BEFORE touching next buffer:
        // its implicit vmcnt(0) drains loads issued one full compute ago.
        __syncthreads();
        issue_loads(1);               // k-chunk k0+1 -> buf1 (overlaps compute)
        compute(&sbuf[0][0]);
        __syncthreads();
        if (k0 + 2 < D_ / BK) issue_loads(0);  // k-chunk k0+2 -> buf0
        compute(&sbuf[1][0]);
    }

    // --- epilogue: exp-form elementwise chain + column (s) reduction ------
    // C/D layout: col = lane&15, row = quad*4 + reg  [m89-verified]
    const bool lastS = (s0 + BM == S_);
    float vsum[2] = {0.f, 0.f};
    #pragma unroll
    for (int n = 0; n < 2; ++n) {
        #pragma unroll
        for (int t = 0; t < 4; ++t) {
            f32x4 fv = acc[0][t][n], iv = acc[1][t][n], hv = acc[2][t][n];
            #pragma unroll
            for (int r = 0; r < 4; ++r) {
                float ef = __expf(-fv[r]);
                float ei = __expf(-iv[r]);
                float af1 = 1.f + ef, ai1 = 1.f + ei;
                float h  = hv[r];
                float eh = __expf(h);
                float g  = (h >= 0.f) ? (h + 0.5f)
                                      : (eh * __builtin_amdgcn_rcpf(1.f + eh));
                vsum[n] += af1 * __builtin_amdgcn_rcpf(ai1) * g;
                if (lastS && wm == 1 && t == 3 && quad == 3 && r == 3) {
                    // this element is global row s = S-1
                    F_ws[(size_t)b * H_ + h0 + wn * 32 + n * 16 + lr] =
                        ai1 * __builtin_amdgcn_rcpf(af1 + ai1);
                }
            }
        }
    }
    #pragma unroll
    for (int n = 0; n < 2; ++n) {
        float v = vsum[n];
        v += __shfl_xor(v, 16, 64);
        v += __shfl_xor(v, 32, 64);
        if (quad == 0) atomicAdd(&colsum[wn * 32 + n * 16 + lr], v);
    }
    __syncthreads();
    if (tid < BN)
        atomicAdd(&acc_ws[(size_t)b * H_ + h0 + tid], colsum[tid]);
}

// out[b,o] = b_out[o] + sum_h w_out[o,h] * F[b,h]*(0.5 + acc[b,h])
__global__ __launch_bounds__(256) void out_gemv(
    const float* __restrict__ wout, const float* __restrict__ bout,
    const float* __restrict__ acc_ws, const float* __restrict__ F_ws,
    float* __restrict__ out)
{
    const int lane = threadIdx.x & 63;
    const int o = blockIdx.x * 4 + (threadIdx.x >> 6);
    float s[B_] = {};
    for (int h = lane; h < H_; h += 64) {
        float w = wout[(size_t)o * H_ + h];
        #pragma unroll
        for (int b = 0; b < B_; ++b) {
            float hv = F_ws[b * H_ + h] * (0.5f + acc_ws[b * H_ + h]);
            s[b] = fmaf(w, hv, s[b]);
        }
    }
    #pragma unroll
    for (int b = 0; b < B_; ++b)
        #pragma unroll
        for (int off = 32; off > 0; off >>= 1)
            s[b] += __shfl_down(s[b], off, 64);
    if (lane == 0) {
        float bo = bout[o];
        #pragma unroll
        for (int b = 0; b < B_; ++b)
            out[(size_t)b * O_ + o] = s[b] + bo;
    }
}

// ---------------------------------------------------------------------------
// fp32 fallback (round-1 kernel) -- used only if ws_size is too small
// ---------------------------------------------------------------------------
constexpr int TS = 64, TH = 64, TK = 16, LDP = 68;

__global__ __launch_bounds__(256) void fused_gemm_reduce(
    const float* __restrict__ x, const float* __restrict__ win,
    float* __restrict__ acc_ws, float* __restrict__ F_ws)
{
    __shared__ __align__(16) float As[TK][LDP];
    __shared__ __align__(16) float Wf[TK][LDP];
    __shared__ __align__(16) float Wi[TK][LDP];
    __shared__ __align__(16) float Wh[TK][LDP];
    __shared__ float colsum[TH];

    const int b  = blockIdx.z;
    const int s0 = blockIdx.x * TS;
    const int h0 = blockIdx.y * TH;
    const int tid = threadIdx.x;
    const int tx = tid & 15;
    const int ty = tid >> 4;

    float accf[4][4] = {};
    float acci[4][4] = {};
    float acch[4][4] = {};

    const int lrow = tid >> 2;
    const int lk4  = (tid & 3) << 2;

    const float* xp  = x   + ((size_t)b * S_ + (s0 + lrow)) * D_ + lk4;
    const float* wfp = win + (size_t)(h0 + lrow) * D_ + lk4;
    const float* wip = wfp + (size_t)H_ * D_;
    const float* whp = wip + (size_t)H_ * D_;

    for (int k0 = 0; k0 < D_; k0 += TK) {
        float4 va = *(const float4*)(xp  + k0);
        float4 vf = *(const float4*)(wfp + k0);
        float4 vi = *(const float4*)(wip + k0);
        float4 vh = *(const float4*)(whp + k0);
        __syncthreads();
        As[lk4+0][lrow]=va.x; As[lk4+1][lrow]=va.y; As[lk4+2][lrow]=va.z; As[lk4+3][lrow]=va.w;
        Wf[lk4+0][lrow]=vf.x; Wf[lk4+1][lrow]=vf.y; Wf[lk4+2][lrow]=vf.z; Wf[lk4+3][lrow]=vf.w;
        Wi[lk4+0][lrow]=vi.x; Wi[lk4+1][lrow]=vi.y; Wi[lk4+2][lrow]=vi.z; Wi[lk4+3][lrow]=vi.w;
        Wh[lk4+0][lrow]=vh.x; Wh[lk4+1][lrow]=vh.y; Wh[lk4+2][lrow]=vh.z; Wh[lk4+3][lrow]=vh.w;
        __syncthreads();
        #pragma unroll
        for (int k = 0; k < TK; ++k) {
            float4 a4 = *(const float4*)&As[k][ty << 2];
            float4 f4 = *(const float4*)&Wf[k][tx << 2];
            float4 i4 = *(const float4*)&Wi[k][tx << 2];
            float4 h4 = *(const float4*)&Wh[k][tx << 2];
            float a[4]  = {a4.x, a4.y, a4.z, a4.w};
            float wf[4] = {f4.x, f4.y, f4.z, f4.w};
            float wi[4] = {i4.x, i4.y, i4.z, i4.w};
            float wh[4] = {h4.x, h4.y, h4.z, h4.w};
            #pragma unroll
            for (int r = 0; r < 4; ++r)
                #pragma unroll
                for (int c = 0; c < 4; ++c) {
                    accf[r][c] = fmaf(a[r], wf[c], accf[r][c]);
                    acci[r][c] = fmaf(a[r], wi[c], acci[r][c]);
                    acch[r][c] = fmaf(a[r], wh[c], acch[r][c]);
                }
        }
    }

    const bool last_s = (s0 + TS == S_);
    float cval[4] = {0.f, 0.f, 0.f, 0.f};
    #pragma unroll
    for (int c = 0; c < 4; ++c)
        #pragma unroll
        for (int r = 0; r < 4; ++r) {
            float f = accf[r][c], i = acci[r][c], h = acch[r][c];
            float d  = softplusf(-f) - softplusf(-i);
            float lg = (h >= 0.f) ? logf(h + 0.5f) : -softplusf(-h);
            cval[c] += expf(d + lg);
            if (last_s && ty == 15 && r == 3)
                F_ws[(size_t)b * H_ + h0 + (tx << 2) + c] = expf(-softplusf(d));
        }
    if (tid < TH) colsum[tid] = 0.f;
    __syncthreads();
    #pragma unroll
    for (int c = 0; c < 4; ++c)
        atomicAdd(&colsum[(tx << 2) + c], cval[c]);
    __syncthreads();
    if (tid < TH)
        atomicAdd(&acc_ws[(size_t)b * H_ + h0 + tid], colsum[tid]);
}

extern "C" void kernel_launch(void* const* d_in, const int* in_sizes, int n_in,
                              void* d_out, int out_size, void* d_ws, size_t ws_size,
                              hipStream_t stream) {
    const float* x    = (const float*)d_in[0];
    const float* w_in = (const float*)d_in[1];
    const float* wout = (const float*)d_in[2];
    const float* bout = (const float*)d_in[3];
    float* out = (float*)d_out;

    float* acc_ws = (float*)d_ws;                 // [B,H] running sums
    float* F_ws   = acc_ws + (size_t)B_ * H_;     // [B,H] exp(log_f at s=S-1)

    hipMemsetAsync(d_ws, 0, 2 * (size_t)B_ * H_ * sizeof(float), stream);

    const size_t nx = (size_t)B_ * S_ * D_;       // 33.5M
    const size_t nw = (size_t)3 * H_ * D_;        // 3.1M
    const size_t bf_off = 32768;                  // past acc/F, 16B aligned
    const size_t need = bf_off + (nx + nw) * sizeof(__bf16);

    if (ws_size >= need) {
        __bf16* xb = (__bf16*)((char*)d_ws + bf_off);
        __bf16* wb = xb + nx;
        int nx8 = (int)(nx / 8), nw8 = (int)(nw / 8);
        cvt_bf16_2<<<(nx8 + nw8 + 255) / 256, 256, 0, stream>>>(
            x, xb, nx8, w_in, wb, nw8);
        gemm_fused_bf16<<<(H_ / BN) * (S_ / BM) * B_, 256, 0, stream>>>(
            xb, wb, acc_ws, F_ws);
    } else {
        dim3 grid(S_ / TS, H_ / TH, B_);
        fused_gemm_reduce<<<grid, 256, 0, stream>>>(x, w_in, acc_ws, F_ws);
    }
    out_gemv<<<O_ / 4, 256, 0, stream>>>(wout, bout, acc_ws, F_ws, out);
}

// Round 6
// 424.979 us; speedup vs baseline: 1.9294x; 1.0959x over previous
//
#include <hip/hip_runtime.h>
#include <math.h>

// Problem constants (fixed by setup_inputs)
constexpr int B_ = 4, S_ = 8192, D_ = 1024, H_ = 1024, O_ = 1024;

typedef __bf16 bf16x8 __attribute__((ext_vector_type(8)));
typedef float  f32x4  __attribute__((ext_vector_type(4)));

__device__ __forceinline__ float softplusf(float x) {
    if (x > 20.f) return x;
    if (x < -20.f) return expf(x);
    return log1pf(expf(x));
}

// ---------------------------------------------------------------------------
// fp32 -> bf16 conversion for BOTH x and w_in in one launch
// (8 elems/thread, 16B stores)
// ---------------------------------------------------------------------------
__global__ __launch_bounds__(256) void cvt_bf16_2(
    const float* __restrict__ srcA, __bf16* __restrict__ dstA, int nA8,
    const float* __restrict__ srcB, __bf16* __restrict__ dstB, int nB8) {
    int i = blockIdx.x * blockDim.x + threadIdx.x;
    const float* src; __bf16* dst;
    if (i < nA8) { src = srcA; dst = dstA; }
    else { i -= nA8; if (i >= nB8) return; src = srcB; dst = dstB; }
    const float4* s = (const float4*)src + (size_t)i * 2;
    float4 a = s[0], b = s[1];
    bf16x8 v = {(__bf16)a.x, (__bf16)a.y, (__bf16)a.z, (__bf16)a.w,
                (__bf16)b.x, (__bf16)b.y, (__bf16)b.z, (__bf16)b.w};
    *((bf16x8*)dst + i) = v;
}

// ---------------------------------------------------------------------------
// bf16 MFMA GEMM (z = x @ w_in^T for 3 gates) fused with elementwise chain
// and s-reduction, double-buffered LDS, exp-form epilogue.
//   h_last[b,h] = F * (0.5 + sum_s term_s)
//   term = (1+e^{-f})/(1+e^{-i}) * g(h);  g(h)= h>=0 ? h+0.5 : e^h/(1+e^h)
//   F (at s=S-1) = (1+e^{-i}) / ((1+e^{-f}) + (1+e^{-i}))
// Block tile: BM=128 (s) x BN=64 (h), BK=32. 4 waves, each 64s x 32h.
//
// __launch_bounds__(256,3): force <=170 unified regs/wave -> 3 waves/SIMD.
// acc=96 + frags ~20 + addressing ~25 fits; watch WRITE_SIZE for spills.
//
// Block-id mapping (XCD locality): all 16 h-tiles of one A panel get ids
// congruent mod 8 -> same XCD under round-robin dispatch, so the 256 KB
// A panel is fetched into ONE XCD's L2 and reused by its 16 h-blocks.
// ---------------------------------------------------------------------------
constexpr int BM = 128, BN = 64, BK = 32;
constexpr int BUF_ELEMS = (BM + 3 * BN) * BK;  // 10240 bf16 = 20 KB

__global__ __launch_bounds__(256, 3) void gemm_fused_bf16(
    const __bf16* __restrict__ xb, const __bf16* __restrict__ wb,
    float* __restrict__ acc_ws, float* __restrict__ F_ws)
{
    __shared__ __bf16 sbuf[2][BUF_ELEMS];   // 40 KB double buffer
    __shared__ float colsum[BN];

    // decode: id = ((pl*16 + hb) * 8) + c ; panel = c*32 + pl
    const int id = blockIdx.x;
    const int c  = id & 7;
    const int q  = id >> 3;          // 0..511
    const int hb = q & 15;
    const int pl = q >> 4;           // 0..31
    const int panel = c * 32 + pl;   // 0..255
    const int sb = panel & 63;
    const int b  = panel >> 6;

    const int h0   = hb * BN;
    const int s0   = sb * BM;
    const int tid  = threadIdx.x;
    const int lane = tid & 63;
    const int wid  = tid >> 6;
    const int wm   = wid >> 1;  // 0..1 : s offset wm*64
    const int wn   = wid & 1;   // 0..1 : h offset wn*32
    const int lr   = lane & 15;
    const int quad = lane >> 4;

    if (tid < BN) colsum[tid] = 0.f;

    // --- staging setup: wave handles wave-loads u = wid*5 + j -------------
    // Each wave-load: 64 lanes x 16B -> 1KB = 16 rows of 32 bf16.
    // LDS dest is wave-uniform base + lane*16 (HW). Global quad
    // qq = sp ^ ((row>>1)&3) goes into slot sp -> compute-side reads are
    // 2-way-max bank aliased (free).
    const __bf16* gptr[5];
    __bf16* lptr[5];
    #pragma unroll
    for (int j = 0; j < 5; ++j) {
        int u  = wid * 5 + j;        // 0..19 : 0-7 = A chunks, 8-19 = B chunks
        int rl = lane >> 2;          // row within 16-row chunk
        int sp = lane & 3;           // slot position
        int off;
        if (u < 8) {
            int row = u * 16 + rl;   // 0..127
            int qq  = sp ^ ((row >> 1) & 3);
            gptr[j] = xb + ((size_t)(b * S_ + s0 + row)) * D_ + qq * 8;
            off = u * 512;
        } else {
            int v   = u - 8;         // g = v>>2, chunk cc = v&3
            int row = (v & 3) * 16 + rl;  // 0..63
            int qq  = sp ^ ((row >> 1) & 3);
            gptr[j] = wb + (size_t)(v >> 2) * H_ * D_ + (size_t)(h0 + row) * D_ + qq * 8;
            off = BM * BK + v * 512;
        }
        lptr[j] = &sbuf[0][off];
    }

    // --- loop-invariant fragment element-offsets ---------------------------
    int aofs[4];
    #pragma unroll
    for (int t = 0; t < 4; ++t) {
        int row  = wm * 64 + t * 16 + lr;
        int slot = quad ^ ((row >> 1) & 3);
        aofs[t] = row * BK + slot * 8;
    }
    int bofs[3][2];
    #pragma unroll
    for (int g = 0; g < 3; ++g)
        #pragma unroll
        for (int n = 0; n < 2; ++n) {
            int row  = wn * 32 + n * 16 + lr;
            int slot = quad ^ ((row >> 1) & 3);
            bofs[g][n] = BM * BK + g * (BN * BK) + row * BK + slot * 8;
        }

    f32x4 acc[3][4][2] = {};

    auto issue_loads = [&](int nxt) {
        #pragma unroll
        for (int j = 0; j < 5; ++j) {
            __builtin_amdgcn_global_load_lds(
                (const __attribute__((address_space(1))) void*)gptr[j],
                (__attribute__((address_space(3))) void*)(lptr[j] + nxt * BUF_ELEMS),
                16, 0, 0);
            gptr[j] += BK;
        }
    };
    auto compute = [&](const __bf16* base) {
        bf16x8 af[4];
        #pragma unroll
        for (int t = 0; t < 4; ++t) af[t] = *(const bf16x8*)(base + aofs[t]);
        #pragma unroll
        for (int g = 0; g < 3; ++g)
            #pragma unroll
            for (int n = 0; n < 2; ++n) {
                bf16x8 bfrag = *(const bf16x8*)(base + bofs[g][n]);
                #pragma unroll
                for (int t = 0; t < 4; ++t)
                    acc[g][t][n] = __builtin_amdgcn_mfma_f32_16x16x32_bf16(
                        af[t], bfrag, acc[g][t][n], 0, 0, 0);
            }
    };

    issue_loads(0);  // k-chunk 0 -> buf0
    for (int k0 = 0; k0 < D_ / BK; k0 += 2) {
        // barrier AFTER compute(prev) and BEFORE touching next buffer:
        // its implicit vmcnt(0) drains loads issued one full compute ago.
        __syncthreads();
        issue_loads(1);               // k-chunk k0+1 -> buf1 (overlaps compute)
        compute(&sbuf[0][0]);
        __syncthreads();
        if (k0 + 2 < D_ / BK) issue_loads(0);  // k-chunk k0+2 -> buf0
        compute(&sbuf[1][0]);
    }

    // --- epilogue: exp-form elementwise chain + column (s) reduction ------
    // C/D layout: col = lane&15, row = quad*4 + reg  [m89-verified]
    const bool lastS = (s0 + BM == S_);
    float vsum[2] = {0.f, 0.f};
    #pragma unroll
    for (int n = 0; n < 2; ++n) {
        #pragma unroll
        for (int t = 0; t < 4; ++t) {
            f32x4 fv = acc[0][t][n], iv = acc[1][t][n], hv = acc[2][t][n];
            #pragma unroll
            for (int r = 0; r < 4; ++r) {
                float ef = __expf(-fv[r]);
                float ei = __expf(-iv[r]);
                float af1 = 1.f + ef, ai1 = 1.f + ei;
                float h  = hv[r];
                float eh = __expf(h);
                float g  = (h >= 0.f) ? (h + 0.5f)
                                      : (eh * __builtin_amdgcn_rcpf(1.f + eh));
                vsum[n] += af1 * __builtin_amdgcn_rcpf(ai1) * g;
                if (lastS && wm == 1 && t == 3 && quad == 3 && r == 3) {
                    // this element is global row s = S-1
                    F_ws[(size_t)b * H_ + h0 + wn * 32 + n * 16 + lr] =
                        ai1 * __builtin_amdgcn_rcpf(af1 + ai1);
                }
            }
        }
    }
    #pragma unroll
    for (int n = 0; n < 2; ++n) {
        float v = vsum[n];
        v += __shfl_xor(v, 16, 64);
        v += __shfl_xor(v, 32, 64);
        if (quad == 0) atomicAdd(&colsum[wn * 32 + n * 16 + lr], v);
    }
    __syncthreads();
    if (tid < BN)
        atomicAdd(&acc_ws[(size_t)b * H_ + h0 + tid], colsum[tid]);
}

// out[b,o] = b_out[o] + sum_h w_out[o,h] * F[b,h]*(0.5 + acc[b,h])
__global__ __launch_bounds__(256) void out_gemv(
    const float* __restrict__ wout, const float* __restrict__ bout,
    const float* __restrict__ acc_ws, const float* __restrict__ F_ws,
    float* __restrict__ out)
{
    const int lane = threadIdx.x & 63;
    const int o = blockIdx.x * 4 + (threadIdx.x >> 6);
    float s[B_] = {};
    for (int h = lane; h < H_; h += 64) {
        float w = wout[(size_t)o * H_ + h];
        #pragma unroll
        for (int b = 0; b < B_; ++b) {
            float hv = F_ws[b * H_ + h] * (0.5f + acc_ws[b * H_ + h]);
            s[b] = fmaf(w, hv, s[b]);
        }
    }
    #pragma unroll
    for (int b = 0; b < B_; ++b)
        #pragma unroll
        for (int off = 32; off > 0; off >>= 1)
            s[b] += __shfl_down(s[b], off, 64);
    if (lane == 0) {
        float bo = bout[o];
        #pragma unroll
        for (int b = 0; b < B_; ++b)
            out[(size_t)b * O_ + o] = s[b] + bo;
    }
}

// ---------------------------------------------------------------------------
// fp32 fallback (round-1 kernel) -- used only if ws_size is too small
// ---------------------------------------------------------------------------
constexpr int TS = 64, TH = 64, TK = 16, LDP = 68;

__global__ __launch_bounds__(256) void fused_gemm_reduce(
    const float* __restrict__ x, const float* __restrict__ win,
    float* __restrict__ acc_ws, float* __restrict__ F_ws)
{
    __shared__ __align__(16) float As[TK][LDP];
    __shared__ __align__(16) float Wf[TK][LDP];
    __shared__ __align__(16) float Wi[TK][LDP];
    __shared__ __align__(16) float Wh[TK][LDP];
    __shared__ float colsum[TH];

    const int b  = blockIdx.z;
    const int s0 = blockIdx.x * TS;
    const int h0 = blockIdx.y * TH;
    const int tid = threadIdx.x;
    const int tx = tid & 15;
    const int ty = tid >> 4;

    float accf[4][4] = {};
    float acci[4][4] = {};
    float acch[4][4] = {};

    const int lrow = tid >> 2;
    const int lk4  = (tid & 3) << 2;

    const float* xp  = x   + ((size_t)b * S_ + (s0 + lrow)) * D_ + lk4;
    const float* wfp = win + (size_t)(h0 + lrow) * D_ + lk4;
    const float* wip = wfp + (size_t)H_ * D_;
    const float* whp = wip + (size_t)H_ * D_;

    for (int k0 = 0; k0 < D_; k0 += TK) {
        float4 va = *(const float4*)(xp  + k0);
        float4 vf = *(const float4*)(wfp + k0);
        float4 vi = *(const float4*)(wip + k0);
        float4 vh = *(const float4*)(whp + k0);
        __syncthreads();
        As[lk4+0][lrow]=va.x; As[lk4+1][lrow]=va.y; As[lk4+2][lrow]=va.z; As[lk4+3][lrow]=va.w;
        Wf[lk4+0][lrow]=vf.x; Wf[lk4+1][lrow]=vf.y; Wf[lk4+2][lrow]=vf.z; Wf[lk4+3][lrow]=vf.w;
        Wi[lk4+0][lrow]=vi.x; Wi[lk4+1][lrow]=vi.y; Wi[lk4+2][lrow]=vi.z; Wi[lk4+3][lrow]=vi.w;
        Wh[lk4+0][lrow]=vh.x; Wh[lk4+1][lrow]=vh.y; Wh[lk4+2][lrow]=vh.z; Wh[lk4+3][lrow]=vh.w;
        __syncthreads();
        #pragma unroll
        for (int k = 0; k < TK; ++k) {
            float4 a4 = *(const float4*)&As[k][ty << 2];
            float4 f4 = *(const float4*)&Wf[k][tx << 2];
            float4 i4 = *(const float4*)&Wi[k][tx << 2];
            float4 h4 = *(const float4*)&Wh[k][tx << 2];
            float a[4]  = {a4.x, a4.y, a4.z, a4.w};
            float wf[4] = {f4.x, f4.y, f4.z, f4.w};
            float wi[4] = {i4.x, i4.y, i4.z, i4.w};
            float wh[4] = {h4.x, h4.y, h4.z, h4.w};
            #pragma unroll
            for (int r = 0; r < 4; ++r)
                #pragma unroll
                for (int c = 0; c < 4; ++c) {
                    accf[r][c] = fmaf(a[r], wf[c], accf[r][c]);
                    acci[r][c] = fmaf(a[r], wi[c], acci[r][c]);
                    acch[r][c] = fmaf(a[r], wh[c], acch[r][c]);
                }
        }
    }

    const bool last_s = (s0 + TS == S_);
    float cval[4] = {0.f, 0.f, 0.f, 0.f};
    #pragma unroll
    for (int c = 0; c < 4; ++c)
        #pragma unroll
        for (int r = 0; r < 4; ++r) {
            float f = accf[r][c], i = acci[r][c], h = acch[r][c];
            float d  = softplusf(-f) - softplusf(-i);
            float lg = (h >= 0.f) ? logf(h + 0.5f) : -softplusf(-h);
            cval[c] += expf(d + lg);
            if (last_s && ty == 15 && r == 3)
                F_ws[(size_t)b * H_ + h0 + (tx << 2) + c] = expf(-softplusf(d));
        }
    if (tid < TH) colsum[tid] = 0.f;
    __syncthreads();
    #pragma unroll
    for (int c = 0; c < 4; ++c)
        atomicAdd(&colsum[(tx << 2) + c], cval[c]);
    __syncthreads();
    if (tid < TH)
        atomicAdd(&acc_ws[(size_t)b * H_ + h0 + tid], colsum[tid]);
}

extern "C" void kernel_launch(void* const* d_in, const int* in_sizes, int n_in,
                              void* d_out, int out_size, void* d_ws, size_t ws_size,
                              hipStream_t stream) {
    const float* x    = (const float*)d_in[0];
    const float* w_in = (const float*)d_in[1];
    const float* wout = (const float*)d_in[2];
    const float* bout = (const float*)d_in[3];
    float* out = (float*)d_out;

    float* acc_ws = (float*)d_ws;                 // [B,H] running sums
    float* F_ws   = acc_ws + (size_t)B_ * H_;     // [B,H] exp(log_f at s=S-1)

    hipMemsetAsync(d_ws, 0, 2 * (size_t)B_ * H_ * sizeof(float), stream);

    const size_t nx = (size_t)B_ * S_ * D_;       // 33.5M
    const size_t nw = (size_t)3 * H_ * D_;        // 3.1M
    const size_t bf_off = 32768;                  // past acc/F, 16B aligned
    const size_t need = bf_off + (nx + nw) * sizeof(__bf16);

    if (ws_size >= need) {
        __bf16* xb = (__bf16*)((char*)d_ws + bf_off);
        __bf16* wb = xb + nx;
        int nx8 = (int)(nx / 8), nw8 = (int)(nw / 8);
        cvt_bf16_2<<<(nx8 + nw8 + 255) / 256, 256, 0, stream>>>(
            x, xb, nx8, w_in, wb, nw8);
        gemm_fused_bf16<<<(H_ / BN) * (S_ / BM) * B_, 256, 0, stream>>>(
            xb, wb, acc_ws, F_ws);
    } else {
        dim3 grid(S_ / TS, H_ / TH, B_);
        fused_gemm_reduce<<<grid, 256, 0, stream>>>(x, w_in, acc_ws, F_ws);
    }
    out_gemv<<<O_ / 4, 256, 0, stream>>>(wout, bout, acc_ws, F_ws, out);
}

// Round 7
// 331.574 us; speedup vs baseline: 2.4729x; 1.2817x over previous
//
#include <hip/hip_runtime.h>
#include <math.h>

// Problem constants (fixed by setup_inputs)
constexpr int B_ = 4, S_ = 8192, D_ = 1024, H_ = 1024, O_ = 1024;

typedef float f32x4  __attribute__((ext_vector_type(4)));
typedef float f32x16 __attribute__((ext_vector_type(16)));
typedef int   i32x4  __attribute__((ext_vector_type(4)));
typedef int   i32x8  __attribute__((ext_vector_type(8)));

__device__ __forceinline__ float softplusf(float x) {
    if (x > 20.f) return x;
    if (x < -20.f) return expf(x);
    return log1pf(expf(x));
}

// ---------------------------------------------------------------------------
// fp32 -> fp8 e4m3 conversion for x (scale 1) and w_in (scale 16, compensated
// by a 2^-4 e8m0 B-scale inside the MFMA). 8 elems/thread.
// ---------------------------------------------------------------------------
__global__ __launch_bounds__(256) void cvt_fp8_2(
    const float* __restrict__ srcA, unsigned char* __restrict__ dstA, int nA8,
    const float* __restrict__ srcB, unsigned char* __restrict__ dstB, int nB8) {
    int i = blockIdx.x * blockDim.x + threadIdx.x;
    const float* src; unsigned char* dst; float sc;
    if (i < nA8) { src = srcA; dst = dstA; sc = 1.f; }
    else { i -= nA8; if (i >= nB8) return; src = srcB; dst = dstB; sc = 16.f; }
    const float4* s = (const float4*)src + (size_t)i * 2;
    float4 a = s[0], b = s[1];
    int lo = __builtin_amdgcn_cvt_pk_fp8_f32(a.x * sc, a.y * sc, 0, false);
    lo     = __builtin_amdgcn_cvt_pk_fp8_f32(a.z * sc, a.w * sc, lo, true);
    int hi = __builtin_amdgcn_cvt_pk_fp8_f32(b.x * sc, b.y * sc, 0, false);
    hi     = __builtin_amdgcn_cvt_pk_fp8_f32(b.z * sc, b.w * sc, hi, true);
    ((int2*)dst)[i] = make_int2(lo, hi);
}

// ---------------------------------------------------------------------------
// Exact F in fp32 (one wave per (b,h)):
//   F = (1+e^{-i}) / ((1+e^{-f}) + (1+e^{-i}))  at s = S-1
// Removes the dominant fp8 error channel (F multiplies the whole output).
// ---------------------------------------------------------------------------
__global__ __launch_bounds__(256) void f_exact(
    const float* __restrict__ x, const float* __restrict__ w_in,
    float* __restrict__ F_ws)
{
    const int lane = threadIdx.x & 63;
    const int pair = blockIdx.x * 4 + (threadIdx.x >> 6);   // 0..4095
    const int b = pair >> 10, h = pair & (H_ - 1);
    const float* xr = x + ((size_t)b * S_ + (S_ - 1)) * D_;
    const float* wf = w_in + (size_t)h * D_;
    const float* wi = wf + (size_t)H_ * D_;
    float sf = 0.f, si = 0.f;
    for (int k = lane; k < D_; k += 64) {
        float xv = xr[k];
        sf = fmaf(xv, wf[k], sf);
        si = fmaf(xv, wi[k], si);
    }
    #pragma unroll
    for (int off = 32; off > 0; off >>= 1) {
        sf += __shfl_xor(sf, off, 64);
        si += __shfl_xor(si, off, 64);
    }
    if (lane == 0) {
        float af1 = 1.f + expf(-sf), ai1 = 1.f + expf(-si);
        F_ws[(size_t)b * H_ + h] = ai1 / (af1 + ai1);
    }
}

// ---------------------------------------------------------------------------
// MX-fp8 MFMA GEMM (z = x @ w_in^T, 3 gates) fused with elementwise chain and
// s-reduction, double-buffered LDS.
//   sum_contrib = (1+e^{-f})/(1+e^{-i}) * g(h);  g(h)=h>=0 ? h+0.5 : sigmoid-ish
// Block tile: BM=128(s) x BN=64(h), BK=64 fp8. 4 waves, each 64s x 32h,
// v_mfma_scale_f32_32x32x64_f8f6f4 (A fmt fp8, B fmt fp8, B scale 2^-4).
// Staging layout: 64 B rows, 4 x 16 B slots, slot = q ^ ((row>>1)&3) swizzle
// (identical bytes to the round-6 bf16 kernel; b128 reads stay conflict-free).
// Block-id mapping: 16 h-tiles of one A panel -> same XCD (round-robin mod 8).
// ---------------------------------------------------------------------------
constexpr int BM = 128, BN = 64, BK = 64;          // BK in fp8 bytes
constexpr int ABYTES = BM * BK;                    // 8192
constexpr int BUF_BYTES = (BM + 3 * BN) * BK;      // 20480

__global__ __launch_bounds__(256, 3) void gemm_fused_fp8(
    const unsigned char* __restrict__ xq, const unsigned char* __restrict__ wq,
    float* __restrict__ acc_ws)
{
    __shared__ unsigned char sbuf[2][BUF_BYTES];   // 40 KB double buffer
    __shared__ float colsum[BN];

    // decode: id = ((pl*16 + hb) * 8) + c ; panel = c*32 + pl
    const int id = blockIdx.x;
    const int c  = id & 7;
    const int q  = id >> 3;
    const int hb = q & 15;
    const int pl = q >> 4;
    const int panel = c * 32 + pl;
    const int sb = panel & 63;
    const int b  = panel >> 6;

    const int h0   = hb * BN;
    const int s0   = sb * BM;
    const int tid  = threadIdx.x;
    const int lane = tid & 63;
    const int wid  = tid >> 6;
    const int wm   = wid >> 1;   // 0..1 : s offset wm*64
    const int wn   = wid & 1;    // 0..1 : h offset wn*32
    const int l31  = lane & 31;
    const int half = lane >> 5;  // k-half for MFMA operand

    if (tid < BN) colsum[tid] = 0.f;

    // --- staging: wave-load u = wid*5 + j; 64 lanes x 16B = 16 rows x 64B ---
    const unsigned char* gptr[5];
    unsigned char* lptr[5];
    #pragma unroll
    for (int j = 0; j < 5; ++j) {
        int u  = wid * 5 + j;        // 0-7 = A chunks, 8-19 = B chunks
        int rl = lane >> 2;          // row within 16-row chunk
        int sp = lane & 3;           // 16B slot within 64B row
        int off;
        if (u < 8) {
            int row = u * 16 + rl;   // 0..127
            int qq  = sp ^ ((row >> 1) & 3);
            gptr[j] = xq + ((size_t)(b * S_ + s0 + row)) * D_ + qq * 16;
            off = u * 1024;
        } else {
            int v   = u - 8;         // gate g = v>>2, chunk = v&3
            int row = (v & 3) * 16 + rl;  // 0..63 within gate tile
            int qq  = sp ^ ((row >> 1) & 3);
            gptr[j] = wq + (size_t)(v >> 2) * H_ * D_ + (size_t)(h0 + row) * D_ + qq * 16;
            off = ABYTES + v * 1024;
        }
        lptr[j] = &sbuf[0][off];
    }

    // --- fragment byte-offsets (two b128 per 32-B operand row-half) -------
    // A[m = l31][k = half*32 + 0..31]; row byte base = row*64; swizzled slots.
    int aof[2][2];
    #pragma unroll
    for (int t = 0; t < 2; ++t) {
        int row = wm * 64 + t * 32 + l31;
        int g2  = (row >> 1) & 3;
        aof[t][0] = row * 64 + ((half * 2)     ^ g2) * 16;
        aof[t][1] = row * 64 + ((half * 2 + 1) ^ g2) * 16;
    }
    int bof[3][2];
    #pragma unroll
    for (int g = 0; g < 3; ++g) {
        int row = wn * 32 + l31;
        int g2  = (row >> 1) & 3;
        bof[g][0] = ABYTES + g * 4096 + row * 64 + ((half * 2)     ^ g2) * 16;
        bof[g][1] = ABYTES + g * 4096 + row * 64 + ((half * 2 + 1) ^ g2) * 16;
    }

    f32x16 acc[3][2] = {};   // [gate][m-tile]

    auto issue_loads = [&](int nxt) {
        #pragma unroll
        for (int j = 0; j < 5; ++j) {
            __builtin_amdgcn_global_load_lds(
                (const __attribute__((address_space(1))) void*)gptr[j],
                (__attribute__((address_space(3))) void*)(lptr[j] + nxt * BUF_BYTES),
                16, 0, 0);
            gptr[j] += BK;
        }
    };
    auto rd8 = [](const unsigned char* base, int o0, int o1) -> i32x8 {
        i32x4 lo = *(const i32x4*)(base + o0);
        i32x4 hi = *(const i32x4*)(base + o1);
        i32x8 r = {lo.x, lo.y, lo.z, lo.w, hi.x, hi.y, hi.z, hi.w};
        return r;
    };
    auto compute = [&](const unsigned char* base) {
        i32x8 af[2];
        #pragma unroll
        for (int t = 0; t < 2; ++t) af[t] = rd8(base, aof[t][0], aof[t][1]);
        #pragma unroll
        for (int g = 0; g < 3; ++g) {
            i32x8 bf = rd8(base, bof[g][0], bof[g][1]);
            #pragma unroll
            for (int t = 0; t < 2; ++t)
                acc[g][t] = __builtin_amdgcn_mfma_scale_f32_32x32x64_f8f6f4(
                    af[t], bf, acc[g][t],
                    0, 0,                     // cbsz=fp8(A), blgp=fp8(B)
                    0, 0x7F7F7F7F,            // A scale = 1.0 (e8m0 127, replicated)
                    0, 0x7B7B7B7B);           // B scale = 2^-4 (w stored x16)
        }
    };

    issue_loads(0);
    constexpr int NC = D_ / BK;   // 16 chunks
    for (int k0 = 0; k0 < NC; k0 += 2) {
        __syncthreads();
        issue_loads(1);
        compute(&sbuf[0][0]);
        __syncthreads();
        if (k0 + 2 < NC) issue_loads(0);
        compute(&sbuf[1][0]);
    }

    // --- epilogue: exp-form chain + column (s) reduction ------------------
    // C/D 32x32 layout: col = lane&31, row = (reg&3) + 8*(reg>>2) + 4*half
    float vsum = 0.f;
    #pragma unroll
    for (int t = 0; t < 2; ++t) {
        f32x16 fv = acc[0][t], iv = acc[1][t], hv = acc[2][t];
        #pragma unroll
        for (int r = 0; r < 16; ++r) {
            float ef = __expf(-fv[r]);
            float ei = __expf(-iv[r]);
            float h  = hv[r];
            float eh = __expf(h);
            float g  = (h >= 0.f) ? (h + 0.5f)
                                  : (eh * __builtin_amdgcn_rcpf(1.f + eh));
            vsum += (1.f + ef) * __builtin_amdgcn_rcpf(1.f + ei) * g;
        }
    }
    vsum += __shfl_xor(vsum, 32, 64);
    if (half == 0) atomicAdd(&colsum[wn * 32 + l31], vsum);
    __syncthreads();
    if (tid < BN)
        atomicAdd(&acc_ws[(size_t)b * H_ + h0 + tid], colsum[tid]);
}

// out[b,o] = b_out[o] + sum_h w_out[o,h] * F[b,h]*(0.5 + acc[b,h])
__global__ __launch_bounds__(256) void out_gemv(
    const float* __restrict__ wout, const float* __restrict__ bout,
    const float* __restrict__ acc_ws, const float* __restrict__ F_ws,
    float* __restrict__ out)
{
    const int lane = threadIdx.x & 63;
    const int o = blockIdx.x * 4 + (threadIdx.x >> 6);
    float s[B_] = {};
    for (int h = lane; h < H_; h += 64) {
        float w = wout[(size_t)o * H_ + h];
        #pragma unroll
        for (int b = 0; b < B_; ++b) {
            float hv = F_ws[b * H_ + h] * (0.5f + acc_ws[b * H_ + h]);
            s[b] = fmaf(w, hv, s[b]);
        }
    }
    #pragma unroll
    for (int b = 0; b < B_; ++b)
        #pragma unroll
        for (int off = 32; off > 0; off >>= 1)
            s[b] += __shfl_down(s[b], off, 64);
    if (lane == 0) {
        float bo = bout[o];
        #pragma unroll
        for (int b = 0; b < B_; ++b)
            out[(size_t)b * O_ + o] = s[b] + bo;
    }
}

// ---------------------------------------------------------------------------
// fp32 fallback (round-1 kernel) -- used only if ws_size is too small
// ---------------------------------------------------------------------------
constexpr int TS = 64, TH = 64, TK = 16, LDP = 68;

__global__ __launch_bounds__(256) void fused_gemm_reduce(
    const float* __restrict__ x, const float* __restrict__ win,
    float* __restrict__ acc_ws, float* __restrict__ F_ws)
{
    __shared__ __align__(16) float As[TK][LDP];
    __shared__ __align__(16) float Wf[TK][LDP];
    __shared__ __align__(16) float Wi[TK][LDP];
    __shared__ __align__(16) float Wh[TK][LDP];
    __shared__ float colsum[TH];

    const int b  = blockIdx.z;
    const int s0 = blockIdx.x * TS;
    const int h0 = blockIdx.y * TH;
    const int tid = threadIdx.x;
    const int tx = tid & 15;
    const int ty = tid >> 4;

    float accf[4][4] = {};
    float acci[4][4] = {};
    float acch[4][4] = {};

    const int lrow = tid >> 2;
    const int lk4  = (tid & 3) << 2;

    const float* xp  = x   + ((size_t)b * S_ + (s0 + lrow)) * D_ + lk4;
    const float* wfp = win + (size_t)(h0 + lrow) * D_ + lk4;
    const float* wip = wfp + (size_t)H_ * D_;
    const float* whp = wip + (size_t)H_ * D_;

    for (int k0 = 0; k0 < D_; k0 += TK) {
        float4 va = *(const float4*)(xp  + k0);
        float4 vf = *(const float4*)(wfp + k0);
        float4 vi = *(const float4*)(wip + k0);
        float4 vh = *(const float4*)(whp + k0);
        __syncthreads();
        As[lk4+0][lrow]=va.x; As[lk4+1][lrow]=va.y; As[lk4+2][lrow]=va.z; As[lk4+3][lrow]=va.w;
        Wf[lk4+0][lrow]=vf.x; Wf[lk4+1][lrow]=vf.y; Wf[lk4+2][lrow]=vf.z; Wf[lk4+3][lrow]=vf.w;
        Wi[lk4+0][lrow]=vi.x; Wi[lk4+1][lrow]=vi.y; Wi[lk4+2][lrow]=vi.z; Wi[lk4+3][lrow]=vi.w;
        Wh[lk4+0][lrow]=vh.x; Wh[lk4+1][lrow]=vh.y; Wh[lk4+2][lrow]=vh.z; Wh[lk4+3][lrow]=vh.w;
        __syncthreads();
        #pragma unroll
        for (int k = 0; k < TK; ++k) {
            float4 a4 = *(const float4*)&As[k][ty << 2];
            float4 f4 = *(const float4*)&Wf[k][tx << 2];
            float4 i4 = *(const float4*)&Wi[k][tx << 2];
            float4 h4 = *(const float4*)&Wh[k][tx << 2];
            float a[4]  = {a4.x, a4.y, a4.z, a4.w};
            float wf[4] = {f4.x, f4.y, f4.z, f4.w};
            float wi[4] = {i4.x, i4.y, i4.z, i4.w};
            float wh[4] = {h4.x, h4.y, h4.z, h4.w};
            #pragma unroll
            for (int r = 0; r < 4; ++r)
                #pragma unroll
                for (int cc = 0; cc < 4; ++cc) {
                    accf[r][cc] = fmaf(a[r], wf[cc], accf[r][cc]);
                    acci[r][cc] = fmaf(a[r], wi[cc], acci[r][cc]);
                    acch[r][cc] = fmaf(a[r], wh[cc], acch[r][cc]);
                }
        }
    }

    const bool last_s = (s0 + TS == S_);
    float cval[4] = {0.f, 0.f, 0.f, 0.f};
    #pragma unroll
    for (int cc = 0; cc < 4; ++cc)
        #pragma unroll
        for (int r = 0; r < 4; ++r) {
            float f = accf[r][cc], i = acci[r][cc], h = acch[r][cc];
            float d  = softplusf(-f) - softplusf(-i);
            float lg = (h >= 0.f) ? logf(h + 0.5f) : -softplusf(-h);
            cval[cc] += expf(d + lg);
            if (last_s && ty == 15 && r == 3)
                F_ws[(size_t)b * H_ + h0 + (tx << 2) + cc] = expf(-softplusf(d));
        }
    if (tid < TH) colsum[tid] = 0.f;
    __syncthreads();
    #pragma unroll
    for (int cc = 0; cc < 4; ++cc)
        atomicAdd(&colsum[(tx << 2) + cc], cval[cc]);
    __syncthreads();
    if (tid < TH)
        atomicAdd(&acc_ws[(size_t)b * H_ + h0 + tid], colsum[tid]);
}

extern "C" void kernel_launch(void* const* d_in, const int* in_sizes, int n_in,
                              void* d_out, int out_size, void* d_ws, size_t ws_size,
                              hipStream_t stream) {
    const float* x    = (const float*)d_in[0];
    const float* w_in = (const float*)d_in[1];
    const float* wout = (const float*)d_in[2];
    const float* bout = (const float*)d_in[3];
    float* out = (float*)d_out;

    float* acc_ws = (float*)d_ws;                 // [B,H] running sums
    float* F_ws   = acc_ws + (size_t)B_ * H_;     // [B,H] exact forget factor

    hipMemsetAsync(d_ws, 0, 2 * (size_t)B_ * H_ * sizeof(float), stream);

    const size_t nx = (size_t)B_ * S_ * D_;       // 33.5M
    const size_t nw = (size_t)3 * H_ * D_;        // 3.1M
    const size_t q_off = 32768;                   // past acc/F, 16B aligned
    const size_t need = q_off + nx + nw;          // fp8: 1 byte/elem

    if (ws_size >= need) {
        unsigned char* xq = (unsigned char*)d_ws + q_off;
        unsigned char* wq = xq + nx;
        int nx8 = (int)(nx / 8), nw8 = (int)(nw / 8);
        cvt_fp8_2<<<(nx8 + nw8 + 255) / 256, 256, 0, stream>>>(
            x, xq, nx8, w_in, wq, nw8);
        f_exact<<<B_ * H_ / 4, 256, 0, stream>>>(x, w_in, F_ws);
        gemm_fused_fp8<<<(H_ / BN) * (S_ / BM) * B_, 256, 0, stream>>>(
            xq, wq, acc_ws);
    } else {
        dim3 grid(S_ / TS, H_ / TH, B_);
        fused_gemm_reduce<<<grid, 256, 0, stream>>>(x, w_in, acc_ws, F_ws);
    }
    out_gemv<<<O_ / 4, 256, 0, stream>>>(wout, bout, acc_ws, F_ws, out);
}